// Round 8
// baseline (964.589 us; speedup 1.0000x reference)
//
#include <hip/hip_runtime.h>
#include <math.h>
#include <cstdint>

#define B_   64
#define N_   2048
#define E_   32768
#define FIN  256
#define H_   512

typedef __bf16 bf16x8 __attribute__((ext_vector_type(8)));
typedef float  f32x4  __attribute__((ext_vector_type(4)));

__device__ __forceinline__ unsigned short f2bf(float f) {
  unsigned u = __float_as_uint(f);
  u += 0x7FFF + ((u >> 16) & 1);            // RNE
  return (unsigned short)(u >> 16);
}
__device__ __forceinline__ unsigned pk2(float a, float b) {
  return (unsigned)f2bf(a) | ((unsigned)f2bf(b) << 16);
}
__device__ __forceinline__ float bflo(unsigned u) { return __uint_as_float(u << 16); }
__device__ __forceinline__ float bfhi(unsigned u) { return __uint_as_float(u & 0xFFFF0000u); }

__device__ __forceinline__ void accum8(float* acc, uint4 u, float c) {
  acc[0] += c * bflo(u.x); acc[1] += c * bfhi(u.x);
  acc[2] += c * bflo(u.y); acc[3] += c * bfhi(u.y);
  acc[4] += c * bflo(u.z); acc[5] += c * bfhi(u.z);
  acc[6] += c * bflo(u.w); acc[7] += c * bfhi(u.w);
}

// async global->LDS, 16B per lane; LDS dest = wave-uniform base + lane*16
__device__ __forceinline__ void glds16(const void* g, void* l) {
  __builtin_amdgcn_global_load_lds(
      (const __attribute__((address_space(1))) unsigned int*)g,
      (__attribute__((address_space(3))) unsigned int*)l, 16, 0, 0);
}

// ---------------- x fp32 -> bf16 ----------------
__global__ void xcvt_k(const float* __restrict__ x, unsigned short* __restrict__ xb) {
  int i = blockIdx.x * 256 + threadIdx.x;   // chunks of 4 floats
  float4 f = reinterpret_cast<const float4*>(x)[i];
  uint2 o; o.x = pk2(f.x, f.y); o.y = pk2(f.z, f.w);
  reinterpret_cast<uint2*>(xb)[i] = o;
}

// ---------------- weight transpose+cast: Wt[n][k] bf16 from W[k][n] fp32 (Nn==512) ----------
__global__ void wcvt_k(const float* __restrict__ W, unsigned short* __restrict__ Wt, int K) {
  int idx = blockIdx.x * 256 + threadIdx.x;     // < K*512
  int k = idx >> 9, n = idx & 511;
  Wt[n * K + k] = f2bf(W[idx]);
}

// ---------------- MFMA GEMM: Y[M,512](bf16) = X[M,K] @ Wt^T, 256x128 tile ----------------
// 256x128 tile (was 128x128): 32 MFMA/wave per BK=32 step -> MFMA issue covers load
// latency; half the blocks/prologue/epilogue per FLOP. Wave w owns rows [w*64, w*64+64)
// x all 128 cols: acc[4][8]. hs row-dots are staged in LDS and stored coalesced to
// hs4[colb][row] (NO global atomics -- 1M L2 atomics were ~50us inside layer-1).
// LDS: As dbuf 2x16KB [0,32K), Bs dbuf 2x8KB [32K,48K). Epilogue reuses [0,34816) as
// 128x272B C staging (two 128-row halves) + hsm[256] floats at [34816,35840).
__global__ __launch_bounds__(256, 2) void gemm_mfma(
    const unsigned short* __restrict__ Xb,
    const int* __restrict__ perm, const float* __restrict__ tanhv,
    const unsigned short* __restrict__ Wt, unsigned short* __restrict__ Y,
    int K, int kl2, int nsl2,
    const float* __restrict__ bias, const float* __restrict__ wp, float* __restrict__ hs4,
    int Mtot) {
  __shared__ __align__(16) char smem[49152];
  const int tid = threadIdx.x;
  const int w = tid >> 6, L = tid & 63;
  const int bid = blockIdx.x;
  const int xcd = bid & 7;
  const int t = bid >> 3;
  const int colb = t & 3;
  const int strip = ((t >> 2) << 3) + xcd;
  const int m0 = strip * 256;
  const int n0 = colb * 128;
  const int e = L & 15, q = L >> 4;

  const int sw3 = (L >> 3) & 7;
  const int lofs = w * 1024;          // wave deposit offset within a 4KB staging call

  f32x4 acc[4][8];
#pragma unroll
  for (int j = 0; j < 4; j++)
#pragma unroll
    for (int nn = 0; nn < 8; nn++) acc[j][nn] = (f32x4){0.f, 0.f, 0.f, 0.f};

  // A staging sources: call i stages positions [i*256, i*256+256) (chunk units)
  size_t asrc[4];
#pragma unroll
  for (int i = 0; i < 4; i++) {
    int cA = (i * 256 + w * 64 + L) ^ sw3;
    int g = m0 + (cA >> 2);
    size_t row;
    if (perm) {
      int b = g >> kl2;
      int node = perm[g];
      row = (size_t)(b << nsl2) + node;
    } else {
      row = (size_t)g;
    }
    asrc[i] = row * (size_t)K + (cA & 3) * 8;
  }
  size_t bsrc[2];
#pragma unroll
  for (int i = 0; i < 2; i++) {
    int cB = (i * 256 + w * 64 + L) ^ sw3;
    bsrc[i] = (size_t)(n0 + (cB >> 2)) * K + (cB & 3) * 8;
  }

  const int fo = e * 4 + q;
  const int fosw = fo ^ (fo >> 3);

  const int nk = K >> 5;
  // prologue: stage step 0 into buffer 0
  {
    char* Ab = smem;
    char* Bb = smem + 32768;
#pragma unroll
    for (int i = 0; i < 4; i++) glds16(Xb + asrc[i], Ab + i * 4096 + lofs);
#pragma unroll
    for (int i = 0; i < 2; i++) glds16(Wt + bsrc[i], Bb + i * 4096 + lofs);
  }
  __syncthreads();
  int cur = 0;
  for (int kt = 0; kt < nk; ++kt) {
    if (kt + 1 < nk) {
      const int k0 = (kt + 1) << 5;
      char* Ab = smem + (cur ^ 1) * 16384;
      char* Bb = smem + 32768 + (cur ^ 1) * 8192;
#pragma unroll
      for (int i = 0; i < 4; i++) glds16(Xb + asrc[i] + k0, Ab + i * 4096 + lofs);
#pragma unroll
      for (int i = 0; i < 2; i++) glds16(Wt + bsrc[i] + k0, Bb + i * 4096 + lofs);
    }
    const uint4* As = (const uint4*)(smem + cur * 16384);
    const uint4* Bs = (const uint4*)(smem + 32768 + cur * 8192);
    bf16x8 af[4], bfr[8];
#pragma unroll
    for (int j = 0; j < 4; j++) af[j]  = __builtin_bit_cast(bf16x8, As[w * 256 + j * 64 + fosw]);
#pragma unroll
    for (int nn = 0; nn < 8; nn++) bfr[nn] = __builtin_bit_cast(bf16x8, Bs[nn * 64 + fosw]);
#pragma unroll
    for (int j = 0; j < 4; j++)
#pragma unroll
      for (int nn = 0; nn < 8; nn++)
        acc[j][nn] = __builtin_amdgcn_mfma_f32_16x16x32_bf16(af[j], bfr[nn], acc[j][nn], 0, 0, 0);
    __syncthreads();
    cur ^= 1;
  }

  // ---- epilogue: two 128-row halves through LDS, coalesced stores ----
  const int RS = 136;                  // row stride in ushorts (272 B)
  unsigned short* Csm = (unsigned short*)smem;
  float* hsm = (float*)(smem + 34816);
  float bs[8], wsv[8];
#pragma unroll
  for (int nn = 0; nn < 8; nn++) {
    int coly = n0 + nn * 16 + e;
    bs[nn]  = bias ? bias[coly] : 0.f;
    wsv[nn] = wp ? wp[coly] : 0.f;
  }
  const int rbase = tid >> 4, ci = tid & 15;
#pragma unroll
  for (int h = 0; h < 2; ++h) {
    if ((w >> 1) == h) {
#pragma unroll
      for (int j = 0; j < 4; j++) {
#pragma unroll
        for (int r = 0; r < 4; r++) {
          int lrow = w * 64 + j * 16 + q * 4 + r;       // [h*128, h*128+128)
          int grow = m0 + lrow;
          float t2 = tanhv ? tanhv[grow] : 1.0f;
          float p = 0.f;
#pragma unroll
          for (int nn = 0; nn < 8; nn++) {
            float v = acc[j][nn][r] * t2;
            if (bias) v = fmaxf(v + bs[nn], 0.f);
            Csm[(lrow - h * 128) * RS + nn * 16 + e] = f2bf(v);
            p += v * wsv[nn];
          }
          if (wp) {
            p += __shfl_xor(p, 1, 64); p += __shfl_xor(p, 2, 64);
            p += __shfl_xor(p, 4, 64); p += __shfl_xor(p, 8, 64);
            if ((L & 15) == 0) hsm[lrow] = p;
          }
        }
      }
    }
    __syncthreads();
#pragma unroll
    for (int pass = 0; pass < 8; ++pass) {
      int lrow = pass * 16 + rbase;
      uint4 u = *(const uint4*)(Csm + lrow * RS + ci * 8);
      *(uint4*)(Y + (size_t)(m0 + h * 128 + lrow) * 512 + n0 + ci * 8) = u;
    }
    __syncthreads();
  }
  if (wp) hs4[(size_t)colb * Mtot + m0 + tid] = hsm[tid];
}

// ---------------- hs partial sum: hs = sum over 4 col-blocks ----------------
__global__ void hsum_k(const float* __restrict__ hs4, float* __restrict__ hs, int M) {
  int i = blockIdx.x * 256 + threadIdx.x;
  hs[i] = hs4[i] + hs4[M + i] + hs4[2 * M + i] + hs4[3 * M + i];
}

// ---------------- fused CSR build v2: coalesced writes only ----------------
template <int NL2, int LEVEL>
__global__ __launch_bounds__(1024) void csr_k(
    const int* __restrict__ src0, const int* __restrict__ dst0,
    const int* __restrict__ curNew, int* __restrict__ cmapG,
    int* __restrict__ rowptr, float* __restrict__ deg,
    int* __restrict__ col, float* __restrict__ ce) {
  const int n = 1 << NL2;
  const int CAP = 8192;
  const int b = blockIdx.x, tid = threadIdx.x;
  __shared__ int   lrp[(1 << NL2) + 1];     // row starts
  __shared__ int   cur[1 << NL2];           // counts -> cursors
  __shared__ float ldv[1 << NL2];
  __shared__ int   ch[1024];
  __shared__ int   cmap[(LEVEL > 0) ? 2048 : 1];
  __shared__ int   scol[CAP];
  __shared__ float sce[CAP];
  __shared__ int   sr1;
  const int eb = b << 15;

  for (int i = tid; i < n; i += 1024) cur[i] = 0;
  if (LEVEL == 1) {
    for (int v = tid; v < 2048; v += 1024) {
      int m = curNew[(b << 11) + v];
      cmap[v] = m;
      cmapG[(b << 11) + v] = m;
    }
  } else if (LEVEL == 2) {
    for (int v = tid; v < 2048; v += 1024) {
      int p = cmapG[(b << 11) + v];
      cmap[v] = (p >= 0) ? curNew[(b << 10) + p] : -1;
    }
  }
  __syncthreads();

  // pass 1: count (LDS atomics)
  for (int e = tid; e < E_; e += 4096) {
#pragma unroll
    for (int u = 0; u < 4; u++) {
      int ei = eb + e + u * 1024;
      int dd = dst0[ei];
      if (LEVEL == 0) {
        atomicAdd(&cur[dd], 1);
      } else {
        int md = cmap[dd], ms = cmap[src0[ei]];
        if (ms >= 0 && md >= 0) atomicAdd(&cur[md], 1);
      }
    }
  }
  __syncthreads();

  // pass 2: scan -> lrp / rowptr / cursor / deg / ldv
  const int nth = (n < 1024) ? n : 1024;
  const int per = (n + 1023) >> 10;         // 2 / 1 / 1
  int lc[per];
  int s = 0;
  if (tid < nth) {
    int base = tid * per;
#pragma unroll
    for (int i = 0; i < per; i++) { lc[i] = cur[base + i]; s += lc[i]; }
  }
  ch[tid] = s;
  __syncthreads();
  for (int off2 = 1; off2 < nth; off2 <<= 1) {
    int v = (tid >= off2) ? ch[tid - off2] : 0;
    __syncthreads();
    ch[tid] += v;
    __syncthreads();
  }
  if (tid < nth) {
    int run = (tid == 0) ? 0 : ch[tid - 1];
    int base = tid * per;
#pragma unroll
    for (int i = 0; i < per; i++) {
      int g = base + i;
      lrp[g] = run;
      rowptr[b * (n + 1) + g] = run;
      cur[g] = run;
      float dd = (float)(lc[i] + 1);
      deg[(b << NL2) + g] = dd;
      ldv[g] = 1.0f / sqrtf(dd);
      run += lc[i];
    }
    if (tid == nth - 1) { lrp[n] = run; rowptr[b * (n + 1) + n] = run; }
  }
  __syncthreads();

  // pass 3: chunked LDS-staged fill, coalesced write-out
  int r0 = 0;
  while (r0 < n) {
    int base0 = lrp[r0];
    if (tid == 0) sr1 = n + 1;
    __syncthreads();
    for (int r = r0 + 1 + tid; r <= n; r += 1024) {
      if (lrp[r] - base0 > CAP) { atomicMin(&sr1, r); break; }
    }
    __syncthreads();
    int r1 = sr1 - 1;
    if (r1 > n) r1 = n;
    if (r1 <= r0) {
      // giant row (>CAP edges): direct global scatter fallback
      for (int e = tid; e < E_; e += 1024) {
        int ei = eb + e;
        int ss = src0[ei], dd = dst0[ei];
        int ms, md;
        if (LEVEL == 0) { ms = ss; md = dd; }
        else { ms = cmap[ss]; md = cmap[dd]; }
        if (ms >= 0 && md == r0) {
          int pos = atomicAdd(&cur[r0], 1);
          col[eb + pos] = ms;
          ce[eb + pos] = ldv[ms] * ldv[r0];
        }
      }
      __syncthreads();
      r0 = r0 + 1;
      continue;
    }
    // stage rows [r0, r1) into LDS
    for (int e = tid; e < E_; e += 4096) {
#pragma unroll
      for (int u = 0; u < 4; u++) {
        int ei = eb + e + u * 1024;
        int ss = src0[ei], dd = dst0[ei];
        int ms, md;
        if (LEVEL == 0) { ms = ss; md = dd; }
        else { ms = cmap[ss]; md = cmap[dd]; }
        if (ms >= 0 && md >= r0 && md < r1) {
          int pos = atomicAdd(&cur[md], 1);
          scol[pos - base0] = ms;
          sce[pos - base0] = ldv[ms] * ldv[md];
        }
      }
    }
    __syncthreads();
    int cnt = lrp[r1] - base0;
    for (int i = tid; i < cnt; i += 1024) {
      col[eb + base0 + i] = scol[i];
      ce[eb + base0 + i] = sce[i];
    }
    __syncthreads();
    r0 = r1;
  }
}

// ---------------- layer-1 aggregation over x (256-wide): Xa = Ahat x  ----------------
__global__ __launch_bounds__(256) void aggx_k(
    const unsigned short* __restrict__ X,
    const int* __restrict__ rowptr, const int* __restrict__ col,
    const float* __restrict__ ce, const float* __restrict__ deg,
    unsigned short* __restrict__ Xa) {
  const int hw = threadIdx.x >> 5, hl = threadIdx.x & 31;
  const int xcd = blockIdx.x & 7;
  const int slot = blockIdx.x >> 3;
  const int gslot = slot >> 8;           // 256 8-node slots per graph
  const int v8 = slot & 255;
  const int b = (gslot << 3) + xcd;
  const int v = v8 * 8 + hw;
  const int bbase = b << 11;
  const int vg = bbase + v;
  const int rb = b * (N_ + 1) + v;
  const int st = rowptr[rb], en = rowptr[rb + 1];
  const int* cb = col + (b << 15);
  const float* cee = ce + (b << 15);
  const unsigned short* Xb_ = X + (size_t)bbase * 256 + hl * 8;
  float acc[8] = {0.f, 0.f, 0.f, 0.f, 0.f, 0.f, 0.f, 0.f};
  int e2 = st;
  for (; e2 + 4 <= en; e2 += 4) {
    int s0 = cb[e2], s1 = cb[e2 + 1], s2 = cb[e2 + 2], s3 = cb[e2 + 3];
    float c0 = cee[e2], c1 = cee[e2 + 1], c2 = cee[e2 + 2], c3 = cee[e2 + 3];
    uint4 u0 = *(const uint4*)(Xb_ + (size_t)s0 * 256);
    uint4 u1 = *(const uint4*)(Xb_ + (size_t)s1 * 256);
    uint4 u2 = *(const uint4*)(Xb_ + (size_t)s2 * 256);
    uint4 u3 = *(const uint4*)(Xb_ + (size_t)s3 * 256);
    accum8(acc, u0, c0); accum8(acc, u1, c1);
    accum8(acc, u2, c2); accum8(acc, u3, c3);
  }
  for (; e2 < en; e2++) {
    uint4 u = *(const uint4*)(Xb_ + (size_t)cb[e2] * 256);
    accum8(acc, u, cee[e2]);
  }
  {
    uint4 u = *(const uint4*)(Xb_ + (size_t)v * 256);
    accum8(acc, u, 1.0f / deg[vg]);
  }
  uint4 o;
  o.x = pk2(acc[0], acc[1]); o.y = pk2(acc[2], acc[3]);
  o.z = pk2(acc[4], acc[5]); o.w = pk2(acc[6], acc[7]);
  *(uint4*)(Xa + (size_t)vg * 256 + hl * 8) = o;
}

// ---------------- GCN aggregate (512-wide) + relu + fused scorer matvec ----------------
template <int NL2>
__global__ __launch_bounds__(256) void agg_k(
    const unsigned short* __restrict__ H,
    const int* __restrict__ rowptr, const int* __restrict__ col,
    const float* __restrict__ ce, const float* __restrict__ deg,
    const float* __restrict__ bias, const float* __restrict__ wp,
    unsigned short* __restrict__ C, float* __restrict__ hs) {
  const int n = 1 << NL2;
  const int xcd = blockIdx.x & 7;
  const int slot = blockIdx.x >> 3;
  const int gslot = slot >> (NL2 - 2);
  const int v4 = slot & ((1 << (NL2 - 2)) - 1);
  const int b = (gslot << 3) + xcd;
  const int w = threadIdx.x >> 6, L = threadIdx.x & 63;
  const int v = v4 * 4 + w;
  const int bbase = b << NL2;
  const int vg = bbase + v;
  const int rb = b * (n + 1) + v;
  const int st = rowptr[rb], en = rowptr[rb + 1];
  const int* cb = col + (b << 15);
  const float* cee = ce + (b << 15);
  const unsigned short* Hb_ = H + (size_t)bbase * 512 + (size_t)L * 8;

  float acc[8] = {0.f, 0.f, 0.f, 0.f, 0.f, 0.f, 0.f, 0.f};
  int e2 = st;
  for (; e2 + 4 <= en; e2 += 4) {
    int s0 = cb[e2], s1 = cb[e2 + 1], s2 = cb[e2 + 2], s3 = cb[e2 + 3];
    float c0 = cee[e2], c1 = cee[e2 + 1], c2 = cee[e2 + 2], c3 = cee[e2 + 3];
    uint4 u0 = *(const uint4*)(Hb_ + (size_t)s0 * 512);
    uint4 u1 = *(const uint4*)(Hb_ + (size_t)s1 * 512);
    uint4 u2 = *(const uint4*)(Hb_ + (size_t)s2 * 512);
    uint4 u3 = *(const uint4*)(Hb_ + (size_t)s3 * 512);
    accum8(acc, u0, c0); accum8(acc, u1, c1);
    accum8(acc, u2, c2); accum8(acc, u3, c3);
  }
  for (; e2 < en; e2++) {
    int s = cb[e2];
    uint4 u = *(const uint4*)(Hb_ + (size_t)s * 512);
    accum8(acc, u, cee[e2]);
  }
  {
    float idg = 1.0f / deg[vg];
    uint4 u = *(const uint4*)(Hb_ + (size_t)v * 512);
    accum8(acc, u, idg);
  }
  float4 bLo = *(const float4*)(bias + L * 8);
  float4 bHi = *(const float4*)(bias + L * 8 + 4);
  acc[0] = fmaxf(acc[0] + bLo.x, 0.f); acc[1] = fmaxf(acc[1] + bLo.y, 0.f);
  acc[2] = fmaxf(acc[2] + bLo.z, 0.f); acc[3] = fmaxf(acc[3] + bLo.w, 0.f);
  acc[4] = fmaxf(acc[4] + bHi.x, 0.f); acc[5] = fmaxf(acc[5] + bHi.y, 0.f);
  acc[6] = fmaxf(acc[6] + bHi.z, 0.f); acc[7] = fmaxf(acc[7] + bHi.w, 0.f);
  uint4 o;
  o.x = pk2(acc[0], acc[1]); o.y = pk2(acc[2], acc[3]);
  o.z = pk2(acc[4], acc[5]); o.w = pk2(acc[6], acc[7]);
  *(uint4*)(C + (size_t)vg * 512 + L * 8) = o;
  float4 wLo = *(const float4*)(wp + L * 8);
  float4 wHi = *(const float4*)(wp + L * 8 + 4);
  float p = acc[0] * wLo.x + acc[1] * wLo.y + acc[2] * wLo.z + acc[3] * wLo.w
          + acc[4] * wHi.x + acc[5] * wHi.y + acc[6] * wHi.z + acc[7] * wHi.w;
#pragma unroll
  for (int off = 32; off > 0; off >>= 1) p += __shfl_down(p, off, 64);
  if (L == 0) hs[vg] = p;
}

__global__ void scoreagg_k(const float* __restrict__ hs, const int* __restrict__ rowptr,
                           const int* __restrict__ col, const float* __restrict__ ce,
                           const float* __restrict__ deg, const float* __restrict__ bp,
                           float* __restrict__ score, int nl2) {
  int idx = blockIdx.x * 256 + threadIdx.x;
  int n = 1 << nl2;
  int b = idx >> nl2, v = idx & (n - 1);
  int rb = b * (n + 1) + v;
  int st = rowptr[rb], en = rowptr[rb + 1];
  const int* cb = col + (b << 15);
  const float* cee = ce + (b << 15);
  int bbase = b << nl2;
  float acc = 0.f;
  int e = st;
  for (; e + 4 <= en; e += 4) {
    acc += hs[bbase + cb[e]] * cee[e] + hs[bbase + cb[e + 1]] * cee[e + 1]
         + hs[bbase + cb[e + 2]] * cee[e + 2] + hs[bbase + cb[e + 3]] * cee[e + 3];
  }
  for (; e < en; e++) acc += hs[bbase + cb[e]] * cee[e];
  score[idx] = acc + hs[idx] / deg[idx] + bp[0];
}

// ---------------- per-batch bitonic top-k (desc score, tie: lower index) ----------------
__global__ __launch_bounds__(1024) void topk_k(const float* __restrict__ score, int* __restrict__ perm,
                                               float* __restrict__ tanhv, int* __restrict__ newidx,
                                               int n, int k) {
  int b = blockIdx.x, tid = threadIdx.x;
  __shared__ float ss[2048];
  __shared__ int si[2048];
  for (int i = tid; i < n; i += 1024) { ss[i] = score[b * n + i]; si[i] = i; }
  __syncthreads();
  for (int size = 2; size <= n; size <<= 1) {
    for (int stride = size >> 1; stride > 0; stride >>= 1) {
      for (int i = tid; i < n; i += 1024) {
        int j = i ^ stride;
        if (j > i) {
          bool up = ((i & size) == 0);
          float fi = ss[i], fj = ss[j];
          int ii = si[i], ij = si[j];
          bool iBefore = (fi > fj) || (fi == fj && ii < ij);
          bool sw = up ? (!iBefore) : iBefore;
          if (sw) { ss[i] = fj; ss[j] = fi; si[i] = ij; si[j] = ii; }
        }
      }
      __syncthreads();
    }
  }
  for (int r = tid; r < n; r += 1024) newidx[b * n + si[r]] = (r < k) ? r : -1;
  for (int r = tid; r < k; r += 1024) { perm[b * k + r] = si[r]; tanhv[b * k + r] = tanhf(ss[r]); }
}

// ---------------- readout stats via gather+scale: partial then reduce ----------------
__global__ __launch_bounds__(512) void statsp_k(const unsigned short* __restrict__ C,
    const int* __restrict__ perm, const float* __restrict__ tv,
    float* __restrict__ zp, int nsl2, int k, int kch) {
  int b = blockIdx.x, rg = blockIdx.y, f = threadIdx.x;
  int r0 = rg * kch;
  float mx = -1e30f, sm = 0.f;
#pragma unroll 4
  for (int r = r0; r < r0 + kch; r++) {
    int node = perm[b * k + r];
    float t = tv[b * k + r];
    float val = __uint_as_float((unsigned)C[((size_t)((b << nsl2) + node)) * 512 + f] << 16) * t;
    mx = fmaxf(mx, val); sm += val;
  }
  zp[(size_t)(b * 8 + rg) * 1024 + f] = mx;
  zp[(size_t)(b * 8 + rg) * 1024 + 512 + f] = sm;
}

__global__ __launch_bounds__(512) void statsr_k(const float* __restrict__ zp,
                                                float* __restrict__ z, int k) {
  int b = blockIdx.x, f = threadIdx.x;
  float mx = -1e30f, sm = 0.f;
#pragma unroll
  for (int g = 0; g < 8; g++) {
    mx = fmaxf(mx, zp[(size_t)(b * 8 + g) * 1024 + f]);
    sm += zp[(size_t)(b * 8 + g) * 1024 + 512 + f];
  }
  z[b * 1024 + f] += mx;
  z[b * 1024 + 512 + f] += sm / (float)k;
}

// ---------------- parallel MLP head: 3 kernels with K-split partials ----------------
__global__ __launch_bounds__(256) void mlp1_k(const float* __restrict__ z,
                                              const float* __restrict__ W1,
                                              float* __restrict__ zp1) {
  const int kc = blockIdx.x & 7;
  const int b = blockIdx.x >> 3;
  const int tid = threadIdx.x;
  __shared__ float zs[128];
  if (tid < 128) zs[tid] = z[b * 1024 + kc * 128 + tid];
  __syncthreads();
  float a0 = 0.f, a1 = 0.f;
  const float* Wb = W1 + (size_t)(kc * 128) * 512 + tid * 2;
#pragma unroll 4
  for (int i = 0; i < 128; i++) {
    float2 w = *(const float2*)(Wb + (size_t)i * 512);
    float zi = zs[i];
    a0 += zi * w.x; a1 += zi * w.y;
  }
  reinterpret_cast<float2*>(zp1 + ((size_t)(kc * 64 + b)) * 512)[tid] = make_float2(a0, a1);
}

__global__ __launch_bounds__(256) void mlp2_k(const float* __restrict__ zp1,
                                              const float* __restrict__ b1,
                                              const float* __restrict__ W2,
                                              float* __restrict__ zp2) {
  const int kc = blockIdx.x & 1;
  const int b = blockIdx.x >> 1;
  const int tid = threadIdx.x;
  __shared__ float z1s[256];
  {
    int i = kc * 256 + tid;
    float a = b1[i];
#pragma unroll
    for (int g = 0; g < 8; g++) a += zp1[((size_t)(g * 64 + b)) * 512 + i];
    z1s[tid] = fmaxf(a, 0.f);
  }
  __syncthreads();
  float a = 0.f;
  const float* Wb = W2 + (size_t)(kc * 256) * 256 + tid;
#pragma unroll 4
  for (int i = 0; i < 256; i++) a += z1s[i] * Wb[(size_t)i * 256];
  zp2[((size_t)(kc * 64 + b)) * 256 + tid] = a;
}

__global__ __launch_bounds__(128) void mlp3_k(const float* __restrict__ zp2,
                                              const float* __restrict__ b2,
                                              const float* __restrict__ piW,
                                              const float* __restrict__ pib,
                                              const float* __restrict__ vW,
                                              const float* __restrict__ vb,
                                              float* __restrict__ out) {
  const int b = blockIdx.x, tid = threadIdx.x;
  __shared__ float z2s[256];
  __shared__ float wred[4];   // [0:2]=wave maxes, [2:4]=wave v-partials
  __shared__ float sred[2];
  for (int t = tid; t < 256; t += 128) {
    float a = b2[t] + zp2[(size_t)b * 256 + t] + zp2[(size_t)(64 + b) * 256 + t];
    z2s[t] = fmaxf(a, 0.f);
  }
  __syncthreads();
  float a = pib[tid];
#pragma unroll 4
  for (int i = 0; i < 256; i++) a += z2s[i] * piW[(size_t)i * 128 + tid];
  float vp = z2s[tid] * vW[tid] + z2s[tid + 128] * vW[tid + 128];
  float m = a;
#pragma unroll
  for (int off = 32; off > 0; off >>= 1) {
    vp += __shfl_xor(vp, off, 64);
    m = fmaxf(m, __shfl_xor(m, off, 64));
  }
  const int wv = tid >> 6;
  if ((tid & 63) == 0) { wred[wv] = m; wred[2 + wv] = vp; }
  __syncthreads();
  m = fmaxf(wred[0], wred[1]);
  float s = expf(a - m);
#pragma unroll
  for (int off = 32; off > 0; off >>= 1) s += __shfl_xor(s, off, 64);
  if ((tid & 63) == 0) sred[wv] = s;
  __syncthreads();
  s = sred[0] + sred[1];
  if (tid == 0) out[B_ * 128 + b] = fmaxf(vb[0] + wred[2] + wred[3], 0.f);
  out[b * 128 + tid] = a - m - logf(s);
}

extern "C" void kernel_launch(void* const* d_in, const int* in_sizes, int n_in,
                              void* d_out, int out_size, void* d_ws, size_t ws_size,
                              hipStream_t stream) {
  const float* x    = (const float*)d_in[0];
  const int*   src0 = (const int*)d_in[1];
  const int*   dst0 = (const int*)d_in[2];
  const float* W1   = (const float*)d_in[3];
  const float* b1   = (const float*)d_in[4];
  const float* Wp1  = (const float*)d_in[5];
  const float* bp1  = (const float*)d_in[6];
  const float* W2   = (const float*)d_in[7];
  const float* b2   = (const float*)d_in[8];
  const float* Wp2  = (const float*)d_in[9];
  const float* bp2  = (const float*)d_in[10];
  const float* W3   = (const float*)d_in[11];
  const float* b3   = (const float*)d_in[12];
  const float* Wp3  = (const float*)d_in[13];
  const float* bp3  = (const float*)d_in[14];
  const float* l1W  = (const float*)d_in[15];
  const float* l1b  = (const float*)d_in[16];
  const float* l2W  = (const float*)d_in[17];
  const float* l2b  = (const float*)d_in[18];
  const float* piW  = (const float*)d_in[19];
  const float* pib  = (const float*)d_in[20];
  const float* vW   = (const float*)d_in[21];
  const float* vb   = (const float*)d_in[22];
  float* out = (float*)d_out;
  (void)in_sizes; (void)n_in; (void)out_size; (void)ws_size;

  // C lives in d_in[0]'s buffer (128 MB): x is dead after xcvt_k; harness restores
  // inputs before every launch.
  unsigned short* Cb = (unsigned short*)d_in[0];

  char* base = (char*)d_ws;
  size_t off = 0;
  auto alloc = [&](size_t bytes) -> void* {
    void* r = base + off;
    off += (bytes + 255) & ~(size_t)255;
    return r;
  };
  unsigned short* Hb   = (unsigned short*)alloc((size_t)B_ * 1024 * H_ * 2);     // 64 MB
  unsigned short* xb   = (unsigned short*)alloc((size_t)B_ * N_ * FIN * 2);      // 64 MB
  unsigned short* Xa   = (unsigned short*)alloc((size_t)B_ * N_ * FIN * 2);      // 64 MB
  unsigned short* W1t  = (unsigned short*)alloc((size_t)512 * 256 * 2);
  unsigned short* W2t  = (unsigned short*)alloc((size_t)512 * 512 * 2);
  unsigned short* W3t  = (unsigned short*)alloc((size_t)512 * 512 * 2);
  int*   col    = (int*)alloc((size_t)B_ * E_ * 4);                              // 8 MB
  float* coefE  = (float*)alloc((size_t)B_ * E_ * 4);                            // 8 MB
  int*   cmapG  = (int*)alloc((size_t)B_ * N_ * 4);                              // composed map
  int*   rowptr = (int*)alloc((size_t)B_ * (N_ + 1) * 4);
  float* deg    = (float*)alloc((size_t)B_ * N_ * 4);
  float* hs     = (float*)alloc((size_t)B_ * N_ * 4);
  float* hs4    = (float*)alloc((size_t)4 * B_ * N_ * 4);                        // 2 MB
  float* score  = (float*)alloc((size_t)B_ * N_ * 4);
  int*   newidx = (int*)alloc((size_t)B_ * N_ * 4);
  int*   perm   = (int*)alloc((size_t)B_ * 1024 * 4);
  float* tanhv  = (float*)alloc((size_t)B_ * 1024 * 4);
  float* zpart  = (float*)alloc((size_t)B_ * 8 * 1024 * 4);
  float* z      = (float*)alloc((size_t)B_ * 1024 * 4);

  // MLP head partials reuse zpart (free after the last statsr_k)
  float* zp1 = zpart;
  float* zp2 = zpart + (size_t)8 * 64 * 512;

  xcvt_k<<<B_ * N_ * FIN / 4 / 256, 256, 0, stream>>>(x, xb);
  wcvt_k<<<256 * 512 / 256, 256, 0, stream>>>(W1, W1t, 256);
  wcvt_k<<<512 * 512 / 256, 256, 0, stream>>>(W2, W2t, 512);
  wcvt_k<<<512 * 512 / 256, 256, 0, stream>>>(W3, W3t, 512);
  hipMemsetAsync(z, 0, (size_t)B_ * 1024 * 4, stream);

  // ========== layer 1: n=2048 (nl2=11), k=1024 ==========
  {
    csr_k<11, 0><<<B_, 1024, 0, stream>>>(src0, dst0, nullptr, nullptr,
                                          rowptr, deg, col, coefE);
    aggx_k<<<B_ * 2048 / 8, 256, 0, stream>>>(xb, rowptr, col, coefE, deg, Xa);
    gemm_mfma<<<B_ * 2048 / 256 * 4, 256, 0, stream>>>(
        Xa, nullptr, nullptr, W1t, Cb, 256, 0, 0, b1, Wp1, hs4, B_ * 2048);
    hsum_k<<<B_ * 2048 / 256, 256, 0, stream>>>(hs4, hs, B_ * 2048);
    scoreagg_k<<<B_ * 2048 / 256, 256, 0, stream>>>(hs, rowptr, col, coefE, deg, bp1, score, 11);
    topk_k<<<B_, 1024, 0, stream>>>(score, perm, tanhv, newidx, 2048, 1024);
    statsp_k<<<dim3(B_, 8), 512, 0, stream>>>(Cb, perm, tanhv, zpart, 11, 1024, 128);
    statsr_k<<<B_, 512, 0, stream>>>(zpart, z, 1024);
    csr_k<10, 1><<<B_, 1024, 0, stream>>>(src0, dst0, newidx, cmapG,
                                          rowptr, deg, col, coefE);
  }
  // ========== layer 2: n=1024 (nl2=10), gather from 2048 (nsl2=11), k=512 ==========
  {
    gemm_mfma<<<B_ * 1024 / 256 * 4, 256, 0, stream>>>(
        Cb, perm, tanhv, W2t, Hb, 512, 10, 11, nullptr, nullptr, nullptr, 0);
    agg_k<10><<<B_ * 1024 / 4, 256, 0, stream>>>(Hb, rowptr, col, coefE, deg, b2, Wp2, Cb, hs);
    scoreagg_k<<<B_ * 1024 / 256, 256, 0, stream>>>(hs, rowptr, col, coefE, deg, bp2, score, 10);
    topk_k<<<B_, 1024, 0, stream>>>(score, perm, tanhv, newidx, 1024, 512);
    statsp_k<<<dim3(B_, 8), 512, 0, stream>>>(Cb, perm, tanhv, zpart, 10, 512, 64);
    statsr_k<<<B_, 512, 0, stream>>>(zpart, z, 512);
    csr_k<9, 2><<<B_, 1024, 0, stream>>>(src0, dst0, newidx, cmapG,
                                         rowptr, deg, col, coefE);
  }
  // ========== layer 3: n=512 (nl2=9), gather from 1024 (nsl2=10), k=256 ==========
  {
    gemm_mfma<<<B_ * 512 / 256 * 4, 256, 0, stream>>>(
        Cb, perm, tanhv, W3t, Hb, 512, 9, 10, nullptr, nullptr, nullptr, 0);
    agg_k<9><<<B_ * 512 / 4, 256, 0, stream>>>(Hb, rowptr, col, coefE, deg, b3, Wp3, Cb, hs);
    scoreagg_k<<<B_ * 512 / 256, 256, 0, stream>>>(hs, rowptr, col, coefE, deg, bp3, score, 9);
    topk_k<<<B_, 1024, 0, stream>>>(score, perm, tanhv, newidx, 512, 256);
    statsp_k<<<dim3(B_, 8), 512, 0, stream>>>(Cb, perm, tanhv, zpart, 9, 256, 32);
    statsr_k<<<B_, 512, 0, stream>>>(zpart, z, 256);
  }

  // ========== MLP head (parallel, fp32) ==========
  mlp1_k<<<B_ * 8, 256, 0, stream>>>(z, l1W, zp1);
  mlp2_k<<<B_ * 2, 256, 0, stream>>>(zp1, l1b, l2W, zp2);
  mlp3_k<<<B_, 128, 0, stream>>>(zp2, l2b, piW, pib, vW, vb, out);
}

// Round 9
// 933.799 us; speedup vs baseline: 1.0330x; 1.0330x over previous
//
#include <hip/hip_runtime.h>
#include <math.h>
#include <cstdint>

#define B_   64
#define N_   2048
#define E_   32768
#define FIN  256
#define H_   512

typedef __bf16 bf16x8 __attribute__((ext_vector_type(8)));
typedef float  f32x4  __attribute__((ext_vector_type(4)));

__device__ __forceinline__ unsigned short f2bf(float f) {
  unsigned u = __float_as_uint(f);
  u += 0x7FFF + ((u >> 16) & 1);            // RNE
  return (unsigned short)(u >> 16);
}
__device__ __forceinline__ unsigned pk2(float a, float b) {
  return (unsigned)f2bf(a) | ((unsigned)f2bf(b) << 16);
}
__device__ __forceinline__ float bflo(unsigned u) { return __uint_as_float(u << 16); }
__device__ __forceinline__ float bfhi(unsigned u) { return __uint_as_float(u & 0xFFFF0000u); }

__device__ __forceinline__ void accum8(float* acc, uint4 u, float c) {
  acc[0] += c * bflo(u.x); acc[1] += c * bfhi(u.x);
  acc[2] += c * bflo(u.y); acc[3] += c * bfhi(u.y);
  acc[4] += c * bflo(u.z); acc[5] += c * bfhi(u.z);
  acc[6] += c * bflo(u.w); acc[7] += c * bfhi(u.w);
}

// async global->LDS, 16B per lane; LDS dest = wave-uniform base + lane*16
__device__ __forceinline__ void glds16(const void* g, void* l) {
  __builtin_amdgcn_global_load_lds(
      (const __attribute__((address_space(1))) unsigned int*)g,
      (__attribute__((address_space(3))) unsigned int*)l, 16, 0, 0);
}

// ---------------- x fp32 -> bf16 ----------------
__global__ void xcvt_k(const float* __restrict__ x, unsigned short* __restrict__ xb) {
  int i = blockIdx.x * 256 + threadIdx.x;   // chunks of 4 floats
  float4 f = reinterpret_cast<const float4*>(x)[i];
  uint2 o; o.x = pk2(f.x, f.y); o.y = pk2(f.z, f.w);
  reinterpret_cast<uint2*>(xb)[i] = o;
}

// ---------------- weight transpose+cast: Wt[n][k] bf16 from W[k][n] fp32 (Nn==512) ----------
__global__ void wcvt_k(const float* __restrict__ W, unsigned short* __restrict__ Wt, int K) {
  int idx = blockIdx.x * 256 + threadIdx.x;     // < K*512
  int k = idx >> 9, n = idx & 511;
  Wt[n * K + k] = f2bf(W[idx]);
}

// ---------------- MFMA GEMM: Y[M,512](bf16) = X[M,K] @ Wt^T, 256x128 tile ----------------
// SWAPPED-OPERAND mfma: acc = mfma(W_frag, X_frag, acc) -> transposed fragment where each
// lane holds 1 row x 4 consecutive cols: C[m = blk + e][n = nn*16 + q*4 + r]. Epilogue
// packs the 4 cols into one uint2 and stores DIRECT to row-major Y -- deletes the whole
// LDS C-staging (128 ds_write_b16 + 2 barriers + 16 reloads per thread, ~30% of r8 VALU).
// Adjacent nn iterations complete each 64B line within one wave -> L2 write-back merges.
// hs row-dot is lane-local; 2 shfl_xor across q-lanes; coalesced 64B store to hs4.
__global__ __launch_bounds__(256, 2) void gemm_mfma(
    const unsigned short* __restrict__ Xb,
    const int* __restrict__ perm, const float* __restrict__ tanhv,
    const unsigned short* __restrict__ Wt, unsigned short* __restrict__ Y,
    int K, int kl2, int nsl2,
    const float* __restrict__ bias, const float* __restrict__ wp, float* __restrict__ hs4,
    int Mtot) {
  __shared__ __align__(16) char smem[49152];   // As dbuf 2x16K [0,32K) | Bs dbuf 2x8K [32K,48K)
  const int tid = threadIdx.x;
  const int w = tid >> 6, L = tid & 63;
  const int bid = blockIdx.x;
  const int xcd = bid & 7;
  const int t = bid >> 3;
  const int colb = t & 3;
  const int strip = ((t >> 2) << 3) + xcd;
  const int m0 = strip * 256;
  const int n0 = colb * 128;
  const int e = L & 15, q = L >> 4;

  const int sw3 = (L >> 3) & 7;
  const int lofs = w * 1024;          // wave deposit offset within a 4KB staging call

  f32x4 acc[4][8];
#pragma unroll
  for (int j = 0; j < 4; j++)
#pragma unroll
    for (int nn = 0; nn < 8; nn++) acc[j][nn] = (f32x4){0.f, 0.f, 0.f, 0.f};

  // A staging sources: call i stages positions [i*256, i*256+256) (chunk units)
  size_t asrc[4];
#pragma unroll
  for (int i = 0; i < 4; i++) {
    int cA = (i * 256 + w * 64 + L) ^ sw3;
    int g = m0 + (cA >> 2);
    size_t row;
    if (perm) {
      int b = g >> kl2;
      int node = perm[g];
      row = (size_t)(b << nsl2) + node;
    } else {
      row = (size_t)g;
    }
    asrc[i] = row * (size_t)K + (cA & 3) * 8;
  }
  size_t bsrc[2];
#pragma unroll
  for (int i = 0; i < 2; i++) {
    int cB = (i * 256 + w * 64 + L) ^ sw3;
    bsrc[i] = (size_t)(n0 + (cB >> 2)) * K + (cB & 3) * 8;
  }

  const int fo = e * 4 + q;
  const int fosw = fo ^ (fo >> 3);

  const int nk = K >> 5;
  // prologue: stage step 0 into buffer 0
  {
    char* Ab = smem;
    char* Bb = smem + 32768;
#pragma unroll
    for (int i = 0; i < 4; i++) glds16(Xb + asrc[i], Ab + i * 4096 + lofs);
#pragma unroll
    for (int i = 0; i < 2; i++) glds16(Wt + bsrc[i], Bb + i * 4096 + lofs);
  }
  __syncthreads();
  int cur = 0;
  for (int kt = 0; kt < nk; ++kt) {
    if (kt + 1 < nk) {
      const int k0 = (kt + 1) << 5;
      char* Ab = smem + (cur ^ 1) * 16384;
      char* Bb = smem + 32768 + (cur ^ 1) * 8192;
#pragma unroll
      for (int i = 0; i < 4; i++) glds16(Xb + asrc[i] + k0, Ab + i * 4096 + lofs);
#pragma unroll
      for (int i = 0; i < 2; i++) glds16(Wt + bsrc[i] + k0, Bb + i * 4096 + lofs);
    }
    const uint4* As = (const uint4*)(smem + cur * 16384);
    const uint4* Bs = (const uint4*)(smem + 32768 + cur * 8192);
    bf16x8 af[4], bfr[8];
#pragma unroll
    for (int j = 0; j < 4; j++) af[j]  = __builtin_bit_cast(bf16x8, As[w * 256 + j * 64 + fosw]);
#pragma unroll
    for (int nn = 0; nn < 8; nn++) bfr[nn] = __builtin_bit_cast(bf16x8, Bs[nn * 64 + fosw]);
#pragma unroll
    for (int j = 0; j < 4; j++)
#pragma unroll
      for (int nn = 0; nn < 8; nn++)
        acc[j][nn] = __builtin_amdgcn_mfma_f32_16x16x32_bf16(bfr[nn], af[j], acc[j][nn], 0, 0, 0);
    __syncthreads();
    cur ^= 1;
  }

  // ---- epilogue: direct row-major uint2 stores (transposed fragment) ----
#pragma unroll
  for (int j = 0; j < 4; j++) {
    int grow = m0 + w * 64 + j * 16 + e;
    float t2 = tanhv ? tanhv[grow] : 1.0f;
    float p = 0.f;
    unsigned short* Yrow = Y + (size_t)grow * 512 + n0 + q * 4;
#pragma unroll
    for (int nn = 0; nn < 8; nn++) {
      int ncol = n0 + nn * 16 + q * 4;
      f32x4 a = acc[j][nn];
      float v0 = a[0] * t2, v1 = a[1] * t2, v2 = a[2] * t2, v3 = a[3] * t2;
      if (bias) {
        float4 bb = *(const float4*)(bias + ncol);
        v0 = fmaxf(v0 + bb.x, 0.f); v1 = fmaxf(v1 + bb.y, 0.f);
        v2 = fmaxf(v2 + bb.z, 0.f); v3 = fmaxf(v3 + bb.w, 0.f);
      }
      if (wp) {
        float4 ww = *(const float4*)(wp + ncol);
        p += v0 * ww.x + v1 * ww.y + v2 * ww.z + v3 * ww.w;
      }
      uint2 o; o.x = pk2(v0, v1); o.y = pk2(v2, v3);
      *(uint2*)(Yrow + nn * 16) = o;
    }
    if (wp) {
      p += __shfl_xor(p, 16, 64);
      p += __shfl_xor(p, 32, 64);
      if (q == 0) hs4[(size_t)colb * Mtot + grow] = p;
    }
  }
}

// ---------------- hs partial sum: hs = sum over 4 col-blocks ----------------
__global__ void hsum_k(const float* __restrict__ hs4, float* __restrict__ hs, int M) {
  int i = blockIdx.x * 256 + threadIdx.x;
  hs[i] = hs4[i] + hs4[M + i] + hs4[2 * M + i] + hs4[3 * M + i];
}

// ---------------- fused CSR build v2: coalesced writes only ----------------
template <int NL2, int LEVEL>
__global__ __launch_bounds__(1024) void csr_k(
    const int* __restrict__ src0, const int* __restrict__ dst0,
    const int* __restrict__ curNew, int* __restrict__ cmapG,
    int* __restrict__ rowptr, float* __restrict__ deg,
    int* __restrict__ col, float* __restrict__ ce) {
  const int n = 1 << NL2;
  const int CAP = 8192;
  const int b = blockIdx.x, tid = threadIdx.x;
  __shared__ int   lrp[(1 << NL2) + 1];     // row starts
  __shared__ int   cur[1 << NL2];           // counts -> cursors
  __shared__ float ldv[1 << NL2];
  __shared__ int   ch[1024];
  __shared__ int   cmap[(LEVEL > 0) ? 2048 : 1];
  __shared__ int   scol[CAP];
  __shared__ float sce[CAP];
  __shared__ int   sr1;
  const int eb = b << 15;

  for (int i = tid; i < n; i += 1024) cur[i] = 0;
  if (LEVEL == 1) {
    for (int v = tid; v < 2048; v += 1024) {
      int m = curNew[(b << 11) + v];
      cmap[v] = m;
      cmapG[(b << 11) + v] = m;
    }
  } else if (LEVEL == 2) {
    for (int v = tid; v < 2048; v += 1024) {
      int p = cmapG[(b << 11) + v];
      cmap[v] = (p >= 0) ? curNew[(b << 10) + p] : -1;
    }
  }
  __syncthreads();

  // pass 1: count (LDS atomics)
  for (int e = tid; e < E_; e += 4096) {
#pragma unroll
    for (int u = 0; u < 4; u++) {
      int ei = eb + e + u * 1024;
      int dd = dst0[ei];
      if (LEVEL == 0) {
        atomicAdd(&cur[dd], 1);
      } else {
        int md = cmap[dd], ms = cmap[src0[ei]];
        if (ms >= 0 && md >= 0) atomicAdd(&cur[md], 1);
      }
    }
  }
  __syncthreads();

  // pass 2: scan -> lrp / rowptr / cursor / deg / ldv
  const int nth = (n < 1024) ? n : 1024;
  const int per = (n + 1023) >> 10;         // 2 / 1 / 1
  int lc[per];
  int s = 0;
  if (tid < nth) {
    int base = tid * per;
#pragma unroll
    for (int i = 0; i < per; i++) { lc[i] = cur[base + i]; s += lc[i]; }
  }
  ch[tid] = s;
  __syncthreads();
  for (int off2 = 1; off2 < nth; off2 <<= 1) {
    int v = (tid >= off2) ? ch[tid - off2] : 0;
    __syncthreads();
    ch[tid] += v;
    __syncthreads();
  }
  if (tid < nth) {
    int run = (tid == 0) ? 0 : ch[tid - 1];
    int base = tid * per;
#pragma unroll
    for (int i = 0; i < per; i++) {
      int g = base + i;
      lrp[g] = run;
      rowptr[b * (n + 1) + g] = run;
      cur[g] = run;
      float dd = (float)(lc[i] + 1);
      deg[(b << NL2) + g] = dd;
      ldv[g] = 1.0f / sqrtf(dd);
      run += lc[i];
    }
    if (tid == nth - 1) { lrp[n] = run; rowptr[b * (n + 1) + n] = run; }
  }
  __syncthreads();

  // pass 3: chunked LDS-staged fill, coalesced write-out
  int r0 = 0;
  while (r0 < n) {
    int base0 = lrp[r0];
    if (tid == 0) sr1 = n + 1;
    __syncthreads();
    for (int r = r0 + 1 + tid; r <= n; r += 1024) {
      if (lrp[r] - base0 > CAP) { atomicMin(&sr1, r); break; }
    }
    __syncthreads();
    int r1 = sr1 - 1;
    if (r1 > n) r1 = n;
    if (r1 <= r0) {
      // giant row (>CAP edges): direct global scatter fallback
      for (int e = tid; e < E_; e += 1024) {
        int ei = eb + e;
        int ss = src0[ei], dd = dst0[ei];
        int ms, md;
        if (LEVEL == 0) { ms = ss; md = dd; }
        else { ms = cmap[ss]; md = cmap[dd]; }
        if (ms >= 0 && md == r0) {
          int pos = atomicAdd(&cur[r0], 1);
          col[eb + pos] = ms;
          ce[eb + pos] = ldv[ms] * ldv[r0];
        }
      }
      __syncthreads();
      r0 = r0 + 1;
      continue;
    }
    // stage rows [r0, r1) into LDS
    for (int e = tid; e < E_; e += 4096) {
#pragma unroll
      for (int u = 0; u < 4; u++) {
        int ei = eb + e + u * 1024;
        int ss = src0[ei], dd = dst0[ei];
        int ms, md;
        if (LEVEL == 0) { ms = ss; md = dd; }
        else { ms = cmap[ss]; md = cmap[dd]; }
        if (ms >= 0 && md >= r0 && md < r1) {
          int pos = atomicAdd(&cur[md], 1);
          scol[pos - base0] = ms;
          sce[pos - base0] = ldv[ms] * ldv[md];
        }
      }
    }
    __syncthreads();
    int cnt = lrp[r1] - base0;
    for (int i = tid; i < cnt; i += 1024) {
      col[eb + base0 + i] = scol[i];
      ce[eb + base0 + i] = sce[i];
    }
    __syncthreads();
    r0 = r1;
  }
}

// ---------------- layer-1 aggregation over x (256-wide): Xa = Ahat x  ----------------
__global__ __launch_bounds__(256) void aggx_k(
    const unsigned short* __restrict__ X,
    const int* __restrict__ rowptr, const int* __restrict__ col,
    const float* __restrict__ ce, const float* __restrict__ deg,
    unsigned short* __restrict__ Xa) {
  const int hw = threadIdx.x >> 5, hl = threadIdx.x & 31;
  const int xcd = blockIdx.x & 7;
  const int slot = blockIdx.x >> 3;
  const int gslot = slot >> 8;           // 256 8-node slots per graph
  const int v8 = slot & 255;
  const int b = (gslot << 3) + xcd;
  const int v = v8 * 8 + hw;
  const int bbase = b << 11;
  const int vg = bbase + v;
  const int rb = b * (N_ + 1) + v;
  const int st = rowptr[rb], en = rowptr[rb + 1];
  const int* cb = col + (b << 15);
  const float* cee = ce + (b << 15);
  const unsigned short* Xb_ = X + (size_t)bbase * 256 + hl * 8;
  float acc[8] = {0.f, 0.f, 0.f, 0.f, 0.f, 0.f, 0.f, 0.f};
  int e2 = st;
  for (; e2 + 4 <= en; e2 += 4) {
    int s0 = cb[e2], s1 = cb[e2 + 1], s2 = cb[e2 + 2], s3 = cb[e2 + 3];
    float c0 = cee[e2], c1 = cee[e2 + 1], c2 = cee[e2 + 2], c3 = cee[e2 + 3];
    uint4 u0 = *(const uint4*)(Xb_ + (size_t)s0 * 256);
    uint4 u1 = *(const uint4*)(Xb_ + (size_t)s1 * 256);
    uint4 u2 = *(const uint4*)(Xb_ + (size_t)s2 * 256);
    uint4 u3 = *(const uint4*)(Xb_ + (size_t)s3 * 256);
    accum8(acc, u0, c0); accum8(acc, u1, c1);
    accum8(acc, u2, c2); accum8(acc, u3, c3);
  }
  for (; e2 < en; e2++) {
    uint4 u = *(const uint4*)(Xb_ + (size_t)cb[e2] * 256);
    accum8(acc, u, cee[e2]);
  }
  {
    uint4 u = *(const uint4*)(Xb_ + (size_t)v * 256);
    accum8(acc, u, 1.0f / deg[vg]);
  }
  uint4 o;
  o.x = pk2(acc[0], acc[1]); o.y = pk2(acc[2], acc[3]);
  o.z = pk2(acc[4], acc[5]); o.w = pk2(acc[6], acc[7]);
  *(uint4*)(Xa + (size_t)vg * 256 + hl * 8) = o;
}

// ---------------- GCN aggregate (512-wide) + relu + fused scorer matvec ----------------
template <int NL2>
__global__ __launch_bounds__(256) void agg_k(
    const unsigned short* __restrict__ H,
    const int* __restrict__ rowptr, const int* __restrict__ col,
    const float* __restrict__ ce, const float* __restrict__ deg,
    const float* __restrict__ bias, const float* __restrict__ wp,
    unsigned short* __restrict__ C, float* __restrict__ hs) {
  const int n = 1 << NL2;
  const int xcd = blockIdx.x & 7;
  const int slot = blockIdx.x >> 3;
  const int gslot = slot >> (NL2 - 2);
  const int v4 = slot & ((1 << (NL2 - 2)) - 1);
  const int b = (gslot << 3) + xcd;
  const int w = threadIdx.x >> 6, L = threadIdx.x & 63;
  const int v = v4 * 4 + w;
  const int bbase = b << NL2;
  const int vg = bbase + v;
  const int rb = b * (n + 1) + v;
  const int st = rowptr[rb], en = rowptr[rb + 1];
  const int* cb = col + (b << 15);
  const float* cee = ce + (b << 15);
  const unsigned short* Hb_ = H + (size_t)bbase * 512 + (size_t)L * 8;

  float acc[8] = {0.f, 0.f, 0.f, 0.f, 0.f, 0.f, 0.f, 0.f};
  int e2 = st;
  for (; e2 + 4 <= en; e2 += 4) {
    int s0 = cb[e2], s1 = cb[e2 + 1], s2 = cb[e2 + 2], s3 = cb[e2 + 3];
    float c0 = cee[e2], c1 = cee[e2 + 1], c2 = cee[e2 + 2], c3 = cee[e2 + 3];
    uint4 u0 = *(const uint4*)(Hb_ + (size_t)s0 * 512);
    uint4 u1 = *(const uint4*)(Hb_ + (size_t)s1 * 512);
    uint4 u2 = *(const uint4*)(Hb_ + (size_t)s2 * 512);
    uint4 u3 = *(const uint4*)(Hb_ + (size_t)s3 * 512);
    accum8(acc, u0, c0); accum8(acc, u1, c1);
    accum8(acc, u2, c2); accum8(acc, u3, c3);
  }
  for (; e2 < en; e2++) {
    int s = cb[e2];
    uint4 u = *(const uint4*)(Hb_ + (size_t)s * 512);
    accum8(acc, u, cee[e2]);
  }
  {
    float idg = 1.0f / deg[vg];
    uint4 u = *(const uint4*)(Hb_ + (size_t)v * 512);
    accum8(acc, u, idg);
  }
  float4 bLo = *(const float4*)(bias + L * 8);
  float4 bHi = *(const float4*)(bias + L * 8 + 4);
  acc[0] = fmaxf(acc[0] + bLo.x, 0.f); acc[1] = fmaxf(acc[1] + bLo.y, 0.f);
  acc[2] = fmaxf(acc[2] + bLo.z, 0.f); acc[3] = fmaxf(acc[3] + bLo.w, 0.f);
  acc[4] = fmaxf(acc[4] + bHi.x, 0.f); acc[5] = fmaxf(acc[5] + bHi.y, 0.f);
  acc[6] = fmaxf(acc[6] + bHi.z, 0.f); acc[7] = fmaxf(acc[7] + bHi.w, 0.f);
  uint4 o;
  o.x = pk2(acc[0], acc[1]); o.y = pk2(acc[2], acc[3]);
  o.z = pk2(acc[4], acc[5]); o.w = pk2(acc[6], acc[7]);
  *(uint4*)(C + (size_t)vg * 512 + L * 8) = o;
  float4 wLo = *(const float4*)(wp + L * 8);
  float4 wHi = *(const float4*)(wp + L * 8 + 4);
  float p = acc[0] * wLo.x + acc[1] * wLo.y + acc[2] * wLo.z + acc[3] * wLo.w
          + acc[4] * wHi.x + acc[5] * wHi.y + acc[6] * wHi.z + acc[7] * wHi.w;
#pragma unroll
  for (int off = 32; off > 0; off >>= 1) p += __shfl_down(p, off, 64);
  if (L == 0) hs[vg] = p;
}

__global__ void scoreagg_k(const float* __restrict__ hs, const int* __restrict__ rowptr,
                           const int* __restrict__ col, const float* __restrict__ ce,
                           const float* __restrict__ deg, const float* __restrict__ bp,
                           float* __restrict__ score, int nl2) {
  int idx = blockIdx.x * 256 + threadIdx.x;
  int n = 1 << nl2;
  int b = idx >> nl2, v = idx & (n - 1);
  int rb = b * (n + 1) + v;
  int st = rowptr[rb], en = rowptr[rb + 1];
  const int* cb = col + (b << 15);
  const float* cee = ce + (b << 15);
  int bbase = b << nl2;
  float acc = 0.f;
  int e = st;
  for (; e + 4 <= en; e += 4) {
    acc += hs[bbase + cb[e]] * cee[e] + hs[bbase + cb[e + 1]] * cee[e + 1]
         + hs[bbase + cb[e + 2]] * cee[e + 2] + hs[bbase + cb[e + 3]] * cee[e + 3];
  }
  for (; e < en; e++) acc += hs[bbase + cb[e]] * cee[e];
  score[idx] = acc + hs[idx] / deg[idx] + bp[0];
}

// ---------------- per-batch bitonic top-k (desc score, tie: lower index) ----------------
__global__ __launch_bounds__(1024) void topk_k(const float* __restrict__ score, int* __restrict__ perm,
                                               float* __restrict__ tanhv, int* __restrict__ newidx,
                                               int n, int k) {
  int b = blockIdx.x, tid = threadIdx.x;
  __shared__ float ss[2048];
  __shared__ int si[2048];
  for (int i = tid; i < n; i += 1024) { ss[i] = score[b * n + i]; si[i] = i; }
  __syncthreads();
  for (int size = 2; size <= n; size <<= 1) {
    for (int stride = size >> 1; stride > 0; stride >>= 1) {
      for (int i = tid; i < n; i += 1024) {
        int j = i ^ stride;
        if (j > i) {
          bool up = ((i & size) == 0);
          float fi = ss[i], fj = ss[j];
          int ii = si[i], ij = si[j];
          bool iBefore = (fi > fj) || (fi == fj && ii < ij);
          bool sw = up ? (!iBefore) : iBefore;
          if (sw) { ss[i] = fj; ss[j] = fi; si[i] = ij; si[j] = ii; }
        }
      }
      __syncthreads();
    }
  }
  for (int r = tid; r < n; r += 1024) newidx[b * n + si[r]] = (r < k) ? r : -1;
  for (int r = tid; r < k; r += 1024) { perm[b * k + r] = si[r]; tanhv[b * k + r] = tanhf(ss[r]); }
}

// ---------------- readout stats via gather+scale: partial then reduce ----------------
__global__ __launch_bounds__(512) void statsp_k(const unsigned short* __restrict__ C,
    const int* __restrict__ perm, const float* __restrict__ tv,
    float* __restrict__ zp, int nsl2, int k, int kch) {
  int b = blockIdx.x, rg = blockIdx.y, f = threadIdx.x;
  int r0 = rg * kch;
  float mx = -1e30f, sm = 0.f;
#pragma unroll 4
  for (int r = r0; r < r0 + kch; r++) {
    int node = perm[b * k + r];
    float t = tv[b * k + r];
    float val = __uint_as_float((unsigned)C[((size_t)((b << nsl2) + node)) * 512 + f] << 16) * t;
    mx = fmaxf(mx, val); sm += val;
  }
  zp[(size_t)(b * 8 + rg) * 1024 + f] = mx;
  zp[(size_t)(b * 8 + rg) * 1024 + 512 + f] = sm;
}

__global__ __launch_bounds__(512) void statsr_k(const float* __restrict__ zp,
                                                float* __restrict__ z, int k) {
  int b = blockIdx.x, f = threadIdx.x;
  float mx = -1e30f, sm = 0.f;
#pragma unroll
  for (int g = 0; g < 8; g++) {
    mx = fmaxf(mx, zp[(size_t)(b * 8 + g) * 1024 + f]);
    sm += zp[(size_t)(b * 8 + g) * 1024 + 512 + f];
  }
  z[b * 1024 + f] += mx;
  z[b * 1024 + 512 + f] += sm / (float)k;
}

// ---------------- parallel MLP head: 3 kernels with K-split partials ----------------
__global__ __launch_bounds__(256) void mlp1_k(const float* __restrict__ z,
                                              const float* __restrict__ W1,
                                              float* __restrict__ zp1) {
  const int kc = blockIdx.x & 7;
  const int b = blockIdx.x >> 3;
  const int tid = threadIdx.x;
  __shared__ float zs[128];
  if (tid < 128) zs[tid] = z[b * 1024 + kc * 128 + tid];
  __syncthreads();
  float a0 = 0.f, a1 = 0.f;
  const float* Wb = W1 + (size_t)(kc * 128) * 512 + tid * 2;
#pragma unroll 4
  for (int i = 0; i < 128; i++) {
    float2 w = *(const float2*)(Wb + (size_t)i * 512);
    float zi = zs[i];
    a0 += zi * w.x; a1 += zi * w.y;
  }
  reinterpret_cast<float2*>(zp1 + ((size_t)(kc * 64 + b)) * 512)[tid] = make_float2(a0, a1);
}

__global__ __launch_bounds__(256) void mlp2_k(const float* __restrict__ zp1,
                                              const float* __restrict__ b1,
                                              const float* __restrict__ W2,
                                              float* __restrict__ zp2) {
  const int kc = blockIdx.x & 1;
  const int b = blockIdx.x >> 1;
  const int tid = threadIdx.x;
  __shared__ float z1s[256];
  {
    int i = kc * 256 + tid;
    float a = b1[i];
#pragma unroll
    for (int g = 0; g < 8; g++) a += zp1[((size_t)(g * 64 + b)) * 512 + i];
    z1s[tid] = fmaxf(a, 0.f);
  }
  __syncthreads();
  float a = 0.f;
  const float* Wb = W2 + (size_t)(kc * 256) * 256 + tid;
#pragma unroll 4
  for (int i = 0; i < 256; i++) a += z1s[i] * Wb[(size_t)i * 256];
  zp2[((size_t)(kc * 64 + b)) * 256 + tid] = a;
}

__global__ __launch_bounds__(128) void mlp3_k(const float* __restrict__ zp2,
                                              const float* __restrict__ b2,
                                              const float* __restrict__ piW,
                                              const float* __restrict__ pib,
                                              const float* __restrict__ vW,
                                              const float* __restrict__ vb,
                                              float* __restrict__ out) {
  const int b = blockIdx.x, tid = threadIdx.x;
  __shared__ float z2s[256];
  __shared__ float wred[4];   // [0:2]=wave maxes, [2:4]=wave v-partials
  __shared__ float sred[2];
  for (int t = tid; t < 256; t += 128) {
    float a = b2[t] + zp2[(size_t)b * 256 + t] + zp2[(size_t)(64 + b) * 256 + t];
    z2s[t] = fmaxf(a, 0.f);
  }
  __syncthreads();
  float a = pib[tid];
#pragma unroll 4
  for (int i = 0; i < 256; i++) a += z2s[i] * piW[(size_t)i * 128 + tid];
  float vp = z2s[tid] * vW[tid] + z2s[tid + 128] * vW[tid + 128];
  float m = a;
#pragma unroll
  for (int off = 32; off > 0; off >>= 1) {
    vp += __shfl_xor(vp, off, 64);
    m = fmaxf(m, __shfl_xor(m, off, 64));
  }
  const int wv = tid >> 6;
  if ((tid & 63) == 0) { wred[wv] = m; wred[2 + wv] = vp; }
  __syncthreads();
  m = fmaxf(wred[0], wred[1]);
  float s = expf(a - m);
#pragma unroll
  for (int off = 32; off > 0; off >>= 1) s += __shfl_xor(s, off, 64);
  if ((tid & 63) == 0) sred[wv] = s;
  __syncthreads();
  s = sred[0] + sred[1];
  if (tid == 0) out[B_ * 128 + b] = fmaxf(vb[0] + wred[2] + wred[3], 0.f);
  out[b * 128 + tid] = a - m - logf(s);
}

extern "C" void kernel_launch(void* const* d_in, const int* in_sizes, int n_in,
                              void* d_out, int out_size, void* d_ws, size_t ws_size,
                              hipStream_t stream) {
  const float* x    = (const float*)d_in[0];
  const int*   src0 = (const int*)d_in[1];
  const int*   dst0 = (const int*)d_in[2];
  const float* W1   = (const float*)d_in[3];
  const float* b1   = (const float*)d_in[4];
  const float* Wp1  = (const float*)d_in[5];
  const float* bp1  = (const float*)d_in[6];
  const float* W2   = (const float*)d_in[7];
  const float* b2   = (const float*)d_in[8];
  const float* Wp2  = (const float*)d_in[9];
  const float* bp2  = (const float*)d_in[10];
  const float* W3   = (const float*)d_in[11];
  const float* b3   = (const float*)d_in[12];
  const float* Wp3  = (const float*)d_in[13];
  const float* bp3  = (const float*)d_in[14];
  const float* l1W  = (const float*)d_in[15];
  const float* l1b  = (const float*)d_in[16];
  const float* l2W  = (const float*)d_in[17];
  const float* l2b  = (const float*)d_in[18];
  const float* piW  = (const float*)d_in[19];
  const float* pib  = (const float*)d_in[20];
  const float* vW   = (const float*)d_in[21];
  const float* vb   = (const float*)d_in[22];
  float* out = (float*)d_out;
  (void)in_sizes; (void)n_in; (void)out_size; (void)ws_size;

  // C lives in d_in[0]'s buffer (128 MB): x is dead after xcvt_k; harness restores
  // inputs before every launch.
  unsigned short* Cb = (unsigned short*)d_in[0];

  char* base = (char*)d_ws;
  size_t off = 0;
  auto alloc = [&](size_t bytes) -> void* {
    void* r = base + off;
    off += (bytes + 255) & ~(size_t)255;
    return r;
  };
  unsigned short* Hb   = (unsigned short*)alloc((size_t)B_ * 1024 * H_ * 2);     // 64 MB
  unsigned short* xb   = (unsigned short*)alloc((size_t)B_ * N_ * FIN * 2);      // 64 MB
  unsigned short* Xa   = (unsigned short*)alloc((size_t)B_ * N_ * FIN * 2);      // 64 MB
  unsigned short* W1t  = (unsigned short*)alloc((size_t)512 * 256 * 2);
  unsigned short* W2t  = (unsigned short*)alloc((size_t)512 * 512 * 2);
  unsigned short* W3t  = (unsigned short*)alloc((size_t)512 * 512 * 2);
  int*   col    = (int*)alloc((size_t)B_ * E_ * 4);                              // 8 MB
  float* coefE  = (float*)alloc((size_t)B_ * E_ * 4);                            // 8 MB
  int*   cmapG  = (int*)alloc((size_t)B_ * N_ * 4);                              // composed map
  int*   rowptr = (int*)alloc((size_t)B_ * (N_ + 1) * 4);
  float* deg    = (float*)alloc((size_t)B_ * N_ * 4);
  float* hs     = (float*)alloc((size_t)B_ * N_ * 4);
  float* hs4    = (float*)alloc((size_t)4 * B_ * N_ * 4);                        // 2 MB
  float* score  = (float*)alloc((size_t)B_ * N_ * 4);
  int*   newidx = (int*)alloc((size_t)B_ * N_ * 4);
  int*   perm   = (int*)alloc((size_t)B_ * 1024 * 4);
  float* tanhv  = (float*)alloc((size_t)B_ * 1024 * 4);
  float* zpart  = (float*)alloc((size_t)B_ * 8 * 1024 * 4);
  float* z      = (float*)alloc((size_t)B_ * 1024 * 4);

  // MLP head partials reuse zpart (free after the last statsr_k)
  float* zp1 = zpart;
  float* zp2 = zpart + (size_t)8 * 64 * 512;

  xcvt_k<<<B_ * N_ * FIN / 4 / 256, 256, 0, stream>>>(x, xb);
  wcvt_k<<<256 * 512 / 256, 256, 0, stream>>>(W1, W1t, 256);
  wcvt_k<<<512 * 512 / 256, 256, 0, stream>>>(W2, W2t, 512);
  wcvt_k<<<512 * 512 / 256, 256, 0, stream>>>(W3, W3t, 512);
  hipMemsetAsync(z, 0, (size_t)B_ * 1024 * 4, stream);

  // ========== layer 1: n=2048 (nl2=11), k=1024 ==========
  {
    csr_k<11, 0><<<B_, 1024, 0, stream>>>(src0, dst0, nullptr, nullptr,
                                          rowptr, deg, col, coefE);
    aggx_k<<<B_ * 2048 / 8, 256, 0, stream>>>(xb, rowptr, col, coefE, deg, Xa);
    gemm_mfma<<<B_ * 2048 / 256 * 4, 256, 0, stream>>>(
        Xa, nullptr, nullptr, W1t, Cb, 256, 0, 0, b1, Wp1, hs4, B_ * 2048);
    hsum_k<<<B_ * 2048 / 256, 256, 0, stream>>>(hs4, hs, B_ * 2048);
    scoreagg_k<<<B_ * 2048 / 256, 256, 0, stream>>>(hs, rowptr, col, coefE, deg, bp1, score, 11);
    topk_k<<<B_, 1024, 0, stream>>>(score, perm, tanhv, newidx, 2048, 1024);
    statsp_k<<<dim3(B_, 8), 512, 0, stream>>>(Cb, perm, tanhv, zpart, 11, 1024, 128);
    statsr_k<<<B_, 512, 0, stream>>>(zpart, z, 1024);
    csr_k<10, 1><<<B_, 1024, 0, stream>>>(src0, dst0, newidx, cmapG,
                                          rowptr, deg, col, coefE);
  }
  // ========== layer 2: n=1024 (nl2=10), gather from 2048 (nsl2=11), k=512 ==========
  {
    gemm_mfma<<<B_ * 1024 / 256 * 4, 256, 0, stream>>>(
        Cb, perm, tanhv, W2t, Hb, 512, 10, 11, nullptr, nullptr, nullptr, 0);
    agg_k<10><<<B_ * 1024 / 4, 256, 0, stream>>>(Hb, rowptr, col, coefE, deg, b2, Wp2, Cb, hs);
    scoreagg_k<<<B_ * 1024 / 256, 256, 0, stream>>>(hs, rowptr, col, coefE, deg, bp2, score, 10);
    topk_k<<<B_, 1024, 0, stream>>>(score, perm, tanhv, newidx, 1024, 512);
    statsp_k<<<dim3(B_, 8), 512, 0, stream>>>(Cb, perm, tanhv, zpart, 10, 512, 64);
    statsr_k<<<B_, 512, 0, stream>>>(zpart, z, 512);
    csr_k<9, 2><<<B_, 1024, 0, stream>>>(src0, dst0, newidx, cmapG,
                                         rowptr, deg, col, coefE);
  }
  // ========== layer 3: n=512 (nl2=9), gather from 1024 (nsl2=10), k=256 ==========
  {
    gemm_mfma<<<B_ * 512 / 256 * 4, 256, 0, stream>>>(
        Cb, perm, tanhv, W3t, Hb, 512, 9, 10, nullptr, nullptr, nullptr, 0);
    agg_k<9><<<B_ * 512 / 4, 256, 0, stream>>>(Hb, rowptr, col, coefE, deg, b3, Wp3, Cb, hs);
    scoreagg_k<<<B_ * 512 / 256, 256, 0, stream>>>(hs, rowptr, col, coefE, deg, bp3, score, 9);
    topk_k<<<B_, 1024, 0, stream>>>(score, perm, tanhv, newidx, 512, 256);
    statsp_k<<<dim3(B_, 8), 512, 0, stream>>>(Cb, perm, tanhv, zpart, 9, 256, 32);
    statsr_k<<<B_, 512, 0, stream>>>(zpart, z, 256);
  }

  // ========== MLP head (parallel, fp32) ==========
  mlp1_k<<<B_ * 8, 256, 0, stream>>>(z, l1W, zp1);
  mlp2_k<<<B_ * 2, 256, 0, stream>>>(zp1, l1b, l2W, zp2);
  mlp3_k<<<B_, 128, 0, stream>>>(zp2, l2b, piW, pib, vW, vb, out);
}